// Round 3
// baseline (355.834 us; speedup 1.0000x reference)
//
#include <hip/hip_runtime.h>
#include <stdint.h>

typedef __bf16 bf16;
typedef __attribute__((ext_vector_type(8))) __bf16 bf16x8;
typedef __attribute__((ext_vector_type(4))) __bf16 bf16x4;
typedef __attribute__((ext_vector_type(4))) float f32x4;

#define LG_D 128

__device__ __forceinline__ void gload_lds16(const void* g, void* l){
  __builtin_amdgcn_global_load_lds(
      (const __attribute__((address_space(1))) void*)g,
      (__attribute__((address_space(3))) void*)l, 16, 0, 0);
}

// ---------------- zero (cnt_in + cnt_out contiguous) ----------------
__global__ void zero_kernel(int* a, int n){
  int i = blockIdx.x * blockDim.x + threadIdx.x;
  if(i < n) a[i] = 0;
}

// ---------------- K1: B granulation (all 4 matrices) + degree histogram ----------------
// granule g=(k8,col): out[g*8+j] = in[k8*8+j][col]; one BK=32 tile = 512
// contiguous granules = 8KB. Pads (k>=Ksrc) are ZERO -> tail/overrun steps
// multiply zero-B, so the GEMM needs no k-guards (uniform vmcnt counts).
// Blocks >= nbig+56 do the edge histogram (independent work, hides its latency).
__global__ void k1_gran_hist(const float* __restrict__ next_h, const float* __restrict__ W_conv,
                             const float* __restrict__ W_fus,  const float* __restrict__ cat_W,
                             bf16* __restrict__ Bg, bf16* __restrict__ Wcg,
                             bf16* __restrict__ Wfg, bf16* __restrict__ catWg,
                             int K, int nbig,
                             const int* __restrict__ src, const int* __restrict__ dst,
                             int* cnt_out, int* cnt_in, int E){
  int b = blockIdx.x;
  const int ngran = nbig + 56;
  if(b >= ngran){
    int e = (b - ngran) * 256 + threadIdx.x;
    if(e < E){
      atomicAdd(&cnt_out[src[e]], 1);
      atomicAdd(&cnt_in[dst[e]], 1);
    }
    return;
  }
  const float* srcp; bf16* dstp; int g0, Ksrc;
  if(b < nbig)          { srcp = next_h; dstp = Bg;    g0 = b * 256;               Ksrc = K;   }
  else if(b < nbig + 16){ srcp = W_conv; dstp = Wcg;   g0 = (b - nbig) * 256;      Ksrc = 128; }
  else if(b < nbig + 32){ srcp = W_fus;  dstp = Wfg;   g0 = (b - nbig - 16) * 256; Ksrc = 128; }
  else                  { srcp = cat_W;  dstp = catWg; g0 = (b - nbig - 32) * 256; Ksrc = 256; }
  int g = g0 + threadIdx.x;
  int k8 = g >> 7, col = g & 127;
  bf16 tmp[8];
  #pragma unroll
  for(int j = 0; j < 8; j++){
    int k = k8 * 8 + j;
    tmp[j] = (k < Ksrc) ? (bf16)srcp[(size_t)k * LG_D + col] : (bf16)0.f;
  }
  *(bf16x8*)(dstp + (size_t)g * 8) = *(bf16x8*)tmp;
}

// ---------------- BM=32 BK=32 depth-2 copy-free pipelined MFMA GEMM body ----------------
// (kept for the short-K GEMMs: curr_h@Wc and final cat GEMM; R0/R1-proven)
#define GB_LOADA(G, S) \
    do{ if(ASRC == 1) loadAb((G), ab[S]); \
        else if(SK == 2) loadA2((G), au0[S], au1[S], av0[S], av1[S]); \
        else loadA1((G), au0[S], au1[S]); }while(0)

#define GB_WAITV() \
    do{ if(ASRC == 1)      asm volatile("s_waitcnt vmcnt(5)" ::: "memory"); \
        else if(SK == 2)   asm volatile("s_waitcnt vmcnt(8)" ::: "memory"); \
        else               asm volatile("s_waitcnt vmcnt(6)" ::: "memory"); }while(0)

#define GB_STEP(S) \
  { \
    GB_WAITV(); \
    __builtin_amdgcn_s_barrier(); \
    __builtin_amdgcn_sched_barrier(0); \
    stageB(step0 + t + 2, (S + 2) % 3); \
    GB_LOADA(step0 + t + 2, (S + 2) % 3); \
    bf16x8 af; \
    if(ASRC == 1) af = ab[S]; \
    else if(SK == 2){ \
      f32x4 s0, s1; \
      s0.x=au0[S].x+av0[S].x; s0.y=au0[S].y+av0[S].y; s0.z=au0[S].z+av0[S].z; s0.w=au0[S].w+av0[S].w; \
      s1.x=au1[S].x+av1[S].x; s1.y=au1[S].y+av1[S].y; s1.z=au1[S].z+av1[S].z; s1.w=au1[S].w+av1[S].w; \
      af = cvt(s0, s1); \
    } else af = cvt(au0[S], au1[S]); \
    const bf16* bp = &Bs[S][(lg * 128 + l16) * 8]; \
    _Pragma("unroll") \
    for(int ni = 0; ni < 8; ni++){ \
      bf16x8 bq = *(const bf16x8*)(bp + ni * 128); \
      acc[ni] = __builtin_amdgcn_mfma_f32_16x16x32_bf16(af, bq, acc[ni], 0, 0, 0); \
    } \
    t++; \
    if(t == nt) goto kdone; \
  }

template<int ASRC, int EPI, int SK>
__device__ __forceinline__ void gemm_body(bf16 (*Bs)[4096], int gx, int gy,
    const float* __restrict__ Af, const bf16* __restrict__ Abf,
    const bf16* __restrict__ Bg,
    float* __restrict__ Cf, bf16* __restrict__ Cb,
    int M, int K, int spc, int TOT, size_t partStride, int yoff,
    const int* __restrict__ cntdeg, const float* __restrict__ bias,
    const float* __restrict__ lng, const float* __restrict__ lnb)
{
  const int tid  = threadIdx.x;
  const int lane = tid & 63, w = tid >> 6;
  const int l16  = lane & 15, lg = lane >> 4;
  const int row0 = gx * 32;
  const int step0 = gy * spc;
  int nt = TOT - step0; if(nt > spc) nt = spc;

  f32x4 acc[8] = {};

  int r = row0 + w * 16 + l16; if(r > M - 1) r = M - 1;   // store is guarded
  const float* Apf = Af  ? Af  + (size_t)r * K + lg * 8 : nullptr;
  const bf16*  Apb = Abf ? Abf + (size_t)r * K + lg * 8 : nullptr;

  f32x4 au0[3], au1[3], av0[3], av1[3];
  bf16x8 ab[3];

  auto stageB = [&](int g, int buf){
    const bf16* sp = Bg + ((size_t)g * 512 + tid) * 8;
    #pragma unroll
    for(int i = 0; i < 4; i++)
      gload_lds16(sp + i * 1024, &Bs[buf][(i * 128 + w * 64) * 8]);
  };
  auto aoff = [&](int g){
    int kk = g * 32;
    return (kk + lg * 8 < K) ? kk : 0;    // OOB k-slots hit zero-B granules
  };
  auto loadA1 = [&](int g, f32x4& u0, f32x4& u1){
    int off = aoff(g);
    u0 = *(const f32x4*)(Apf + off);
    u1 = *(const f32x4*)(Apf + off + 4);
  };
  auto loadA2 = [&](int g, f32x4& u0, f32x4& u1, f32x4& v0, f32x4& v1){
    int off = aoff(g);
    u0 = *(const f32x4*)(Apf + off);
    u1 = *(const f32x4*)(Apf + off + 4);
    v0 = *(const f32x4*)(Apf + partStride + off);
    v1 = *(const f32x4*)(Apf + partStride + off + 4);
  };
  auto loadAb = [&](int g, bf16x8& b){
    int off = aoff(g);
    b = *(const bf16x8*)(Apb + off);
  };
  auto cvt = [&](const f32x4& u0, const f32x4& u1){
    bf16x8 a;
    a[0]=(bf16)u0.x; a[1]=(bf16)u0.y; a[2]=(bf16)u0.z; a[3]=(bf16)u0.w;
    a[4]=(bf16)u1.x; a[5]=(bf16)u1.y; a[6]=(bf16)u1.z; a[7]=(bf16)u1.w;
    return a;
  };

  // prologue: issue sets for tiles step0, step0+1 into slots 0,1
  stageB(step0, 0);     GB_LOADA(step0, 0);
  stageB(step0 + 1, 1); GB_LOADA(step0 + 1, 1);

  {
    int t = 0;
    while(true){
      GB_STEP(0)
      GB_STEP(1)
      GB_STEP(2)
    }
  }
kdone:

  // ---- epilogues (C/D layout: col = l16, row = lg*4 + j; m89-verified) ----
  if(EPI == 0){
    float* Co = Cf + (size_t)gy * partStride;
    #pragma unroll
    for(int j = 0; j < 4; j++){
      int rr = row0 + w * 16 + lg * 4 + j;
      if(rr < M){
        #pragma unroll
        for(int ni = 0; ni < 8; ni++)
          Co[(size_t)rr * LG_D + ni * 16 + l16] = acc[ni][j];
      }
    }
  } else if(EPI == 1){
    #pragma unroll
    for(int j = 0; j < 4; j++){
      int rr = row0 + w * 16 + lg * 4 + j;
      if(rr < M){
        float sc = rsqrtf((float)(cntdeg[rr] + 1));
        #pragma unroll
        for(int ni = 0; ni < 8; ni++)
          Cb[(size_t)rr * 256 + yoff + ni * 16 + l16] = (bf16)(acc[ni][j] * sc);
      }
    }
  } else {
    float gg[8], bbta[8], bs[8];
    #pragma unroll
    for(int ni = 0; ni < 8; ni++){
      int col = ni * 16 + l16;
      gg[ni] = lng[col]; bbta[ni] = lnb[col]; bs[ni] = bias[col];
    }
    #pragma unroll
    for(int j = 0; j < 4; j++){
      int rr = row0 + w * 16 + lg * 4 + j;
      float v[8]; float s1 = 0.f, s2 = 0.f;
      #pragma unroll
      for(int ni = 0; ni < 8; ni++){
        v[ni] = acc[ni][j] + bs[ni];
        s1 += v[ni]; s2 += v[ni] * v[ni];
      }
      #pragma unroll
      for(int off = 1; off < 16; off <<= 1){
        s1 += __shfl_xor(s1, off, 64);
        s2 += __shfl_xor(s2, off, 64);
      }
      float mu  = s1 * (1.f / 128.f);
      float inv = rsqrtf(s2 * (1.f / 128.f) - mu * mu + 1e-5f);
      if(rr < M){
        #pragma unroll
        for(int ni = 0; ni < 8; ni++)
          Cf[(size_t)rr * LG_D + ni * 16 + l16] = (v[ni] - mu) * inv * gg[ni] + bbta[ni];
      }
    }
  }
}

// ---------------- 128-thread exclusive scan (rides inside the mega dispatch) ----------------
__device__ void scan_body(const int* __restrict__ cnt, int* __restrict__ q, int n, int* sh){
  const int tid = threadIdx.x;
  const int lane = tid & 63, wid = tid >> 6;
  int carry = 0;
  for(int base = 0; base < n; base += 128){
    int i = base + tid;
    int v = (i < n) ? cnt[i] : 0;
    int x = v;
    #pragma unroll
    for(int off = 1; off < 64; off <<= 1){
      int y = __shfl_up(x, off, 64);
      if(lane >= off) x += y;
    }
    if(lane == 63) sh[wid] = x;
    __syncthreads();
    int w0 = sh[0], w1 = sh[1];
    int excl = x - v + (wid ? w0 : 0) + carry;
    if(i < n) q[i] = excl;
    carry += w0 + w1;
    __syncthreads();
  }
}

// ---------------- K2 mega: depth-3 no-split-K inc-GEMM with in-block W_fus fusion ----------------
// blocks [0,gm): fused = inc @ Bg (313 steps, depth-3 pipeline, vmcnt(12)),
//                then H[:,128:256] = (fused @ W_fus) * rsqrt(deg_out).
//                Fuse phase is BARRIER-FREE: A from an 8KB XOR-swizzled LDS
//                transpose (written once, drained by __syncthreads), B-frags
//                read directly from global Wfg (64KB, L2-hot) -> no LDS buffer
//                is ever overwritten during the fuse GEMM -> no read/write race.
// blocks [gm,2gm): H[:,0:128] = (curr_h @ W_conv) * rsqrt(deg_out) (gemm_body).
// block 2gm: exclusive scan of cnt_in -> q (hidden under the BW-bound stream).
__global__ __launch_bounds__(128, 2) void k2_mega(
    const float* __restrict__ inc, const bf16* __restrict__ Bg,
    const bf16* __restrict__ Wfg, const bf16* __restrict__ Wcg,
    const float* __restrict__ curr_h, bf16* __restrict__ H,
    int M, int K, int TOT, const int* __restrict__ cnt_out,
    const int* __restrict__ cnt_in, int* __restrict__ q, int gm){
  __shared__ bf16 Bs[4][4096];          // 32KB -> 5 blocks/CU; Bs[3] doubles as As
  const int bx = blockIdx.x;
  if(bx >= 2 * gm){
    if(bx == 2 * gm) scan_body(cnt_in, q, M, (int*)&Bs[0][0]);
    return;
  }
  if(bx >= gm){
    gemm_body<0, 1, 1>(Bs, bx - gm, 0, curr_h, nullptr, Wcg, nullptr, H,
                       M, 128, 4, 4, 0, 0, cnt_out, nullptr, nullptr, nullptr);
    return;
  }

  const int tid  = threadIdx.x;
  const int lane = tid & 63, w = tid >> 6;
  const int l16  = lane & 15, lg = lane >> 4;
  const int row0 = bx * 32;

  f32x4 acc[8] = {};
  int r = row0 + w * 16 + l16; if(r > M - 1) r = M - 1;   // store is guarded
  const float* Ap = inc + (size_t)r * K + lg * 8;

  f32x4 au0[4], au1[4];
  auto stage = [&](int g, int buf){
    const bf16* sp = Bg + ((size_t)g * 512 + tid) * 8;
    #pragma unroll
    for(int i = 0; i < 4; i++)
      gload_lds16(sp + i * 1024, &Bs[buf][(i * 128 + w * 64) * 8]);
  };
  auto loadA = [&](int g, f32x4& u0, f32x4& u1){
    int kk = g * 32;
    int off = (kk + lg * 8 < K) ? kk : 0;   // OOB k-slots hit zero-B granules
    u0 = *(const f32x4*)(Ap + off);
    u1 = *(const f32x4*)(Ap + off + 4);
  };
  auto cvt8 = [&](const f32x4& u0, const f32x4& u1){
    bf16x8 a;
    a[0]=(bf16)u0.x; a[1]=(bf16)u0.y; a[2]=(bf16)u0.z; a[3]=(bf16)u0.w;
    a[4]=(bf16)u1.x; a[5]=(bf16)u1.y; a[6]=(bf16)u1.z; a[7]=(bf16)u1.w;
    return a;
  };

  // prologue: 3 sets in flight (each set = 4 B-gloads + 2 A-loads = 6 VMEM)
  stage(0, 0); loadA(0, au0[0], au1[0]);
  stage(1, 1); loadA(1, au0[1], au1[1]);
  stage(2, 2); loadA(2, au0[2], au1[2]);

// lgkmcnt(0) is ~free here (all ds_reads already consumed by step t-1's MFMAs)
// but guarantees no LDS read is outstanding when stage(t+3) overwrites a buffer.
#define G3_STEP(S) \
  { \
    asm volatile("s_waitcnt vmcnt(12) lgkmcnt(0)" ::: "memory"); \
    __builtin_amdgcn_s_barrier(); \
    __builtin_amdgcn_sched_barrier(0); \
    stage(t + 3, (S + 3) & 3); \
    loadA(t + 3, au0[(S + 3) & 3], au1[(S + 3) & 3]); \
    bf16x8 af = cvt8(au0[S], au1[S]); \
    const bf16* bp = &Bs[S][(lg * 128 + l16) * 8]; \
    _Pragma("unroll") \
    for(int ni = 0; ni < 8; ni++){ \
      bf16x8 bq = *(const bf16x8*)(bp + ni * 128); \
      acc[ni] = __builtin_amdgcn_mfma_f32_16x16x32_bf16(af, bq, acc[ni], 0, 0, 0); \
    } \
    t++; \
    if(t == TOT) goto fuse; \
  }

  {
    int t = 0;
    while(true){
      G3_STEP(0)
      G3_STEP(1)
      G3_STEP(2)
      G3_STEP(3)
    }
  }
fuse:
  {
    // drain overrun prefetch (vm) and any LDS reads (lgkm); sync waves; pin.
    asm volatile("s_waitcnt vmcnt(0) lgkmcnt(0)" ::: "memory");
    __builtin_amdgcn_s_barrier();
    __builtin_amdgcn_sched_barrier(0);

    // acc (col=l16+16ni, row=w*16+lg*4+j) -> As (Bs[3]) as bf16, XOR-swizzled:
    // byte = (row*256 + col*2) ^ ((row&7)<<4)  -> conflict-free b128 re-reads
    char* Asp = (char*)&Bs[3][0];
    #pragma unroll
    for(int ni = 0; ni < 8; ni++){
      #pragma unroll
      for(int j = 0; j < 4; j++){
        int row = w * 16 + lg * 4 + j;
        int off = ((row * 256 + (ni * 16 + l16) * 2) ^ ((row & 7) << 4));
        *(bf16*)(Asp + off) = (bf16)acc[ni][j];
      }
    }
    __syncthreads();   // As writes drained (lgkmcnt 0) + wave sync

    // fused @ W_fus: A-frag from As (each wave reads only its own rows),
    // B-frags straight from global Wfg (L2-hot). NO barriers, NO overwrites.
    f32x4 acc2[8] = {};
    const int rowA = w * 16 + l16;
    #pragma unroll
    for(int t2 = 0; t2 < 4; t2++){
      int aoff2 = ((rowA * 256 + t2 * 64 + lg * 16) ^ ((rowA & 7) << 4));
      bf16x8 af2 = *(const bf16x8*)(Asp + aoff2);
      const bf16* wp = Wfg + (size_t)((t2 * 4 + lg) * 128) * 8;
      #pragma unroll
      for(int ni = 0; ni < 8; ni++){
        bf16x8 bq = *(const bf16x8*)(wp + (ni * 16 + l16) * 8);
        acc2[ni] = __builtin_amdgcn_mfma_f32_16x16x32_bf16(af2, bq, acc2[ni], 0, 0, 0);
      }
    }

    #pragma unroll
    for(int j = 0; j < 4; j++){
      int rr = row0 + w * 16 + lg * 4 + j;
      if(rr < M){
        float sc = rsqrtf((float)(cnt_out[rr] + 1));
        #pragma unroll
        for(int ni = 0; ni < 8; ni++)
          H[(size_t)rr * 256 + 128 + ni * 16 + l16] = (bf16)(acc2[ni][j] * sc);
      }
    }
  }
#undef G3_STEP
}

// ---------------- K3: CSR scatter (q: starts -> ends) ----------------
__global__ void k3_scatter(const int* __restrict__ src, const int* __restrict__ dst,
                           int* __restrict__ q, int* __restrict__ csr, int E){
  int e = blockIdx.x * blockDim.x + threadIdx.x;
  if(e < E){
    int d = dst[e];
    int pos = atomicAdd(&q[d], 1);
    csr[pos] = src[e];
  }
}

// ---------------- fused SpMM (1 wave per row, bf16x4/lane, 2-deep gather pipeline) ----------------
__global__ __launch_bounds__(256) void spmm_fuse_kernel(const bf16* __restrict__ H,
    const int* __restrict__ q, const int* __restrict__ csr,
    const float* __restrict__ b_conv, const float* __restrict__ conv_w,
    const float* __restrict__ b_fus,  const float* __restrict__ td_w,
    bf16* __restrict__ V, int M){
  const int lane = threadIdx.x & 63;
  const int row  = blockIdx.x * 4 + (threadIdx.x >> 6);
  if(row >= M) return;
  const int end = q[row];
  const int beg = row ? q[row - 1] : 0;
  const int n   = end - beg;

  float acc[4];
  {
    bf16x4 h = *(const bf16x4*)(H + (size_t)row * 256 + lane * 4);   // self-loop
    #pragma unroll
    for(int j = 0; j < 4; j++) acc[j] = (float)h[j];
  }
  bf16x4 f0, f1;
  if(n > 0) f0 = *(const bf16x4*)(H + (size_t)csr[beg] * 256 + lane * 4);
  if(n > 1) f1 = *(const bf16x4*)(H + (size_t)csr[beg + 1] * 256 + lane * 4);
  int i = 0;
  for(; i + 2 < n; i++){
    bf16x4 c = f0; f0 = f1;
    f1 = *(const bf16x4*)(H + (size_t)csr[beg + i + 2] * 256 + lane * 4);
    #pragma unroll
    for(int j = 0; j < 4; j++) acc[j] += (float)c[j];
  }
  if(i < n){
    #pragma unroll
    for(int j = 0; j < 4; j++) acc[j] += (float)f0[j];
    i++;
  }
  if(i < n){
    #pragma unroll
    for(int j = 0; j < 4; j++) acc[j] += (float)f1[j];
  }

  float rs = rsqrtf((float)(n + 1));                // deg_in
  const bool low = lane < 32;
  const int ci = low ? lane * 4 : (lane - 32) * 4;
  const float* bp_ = low ? b_conv : b_fus;
  const float* wp_ = low ? conv_w : td_w;
  float mine[4], other[4];
  #pragma unroll
  for(int j = 0; j < 4; j++)
    mine[j] = (acc[j] * rs + bp_[ci + j]) * wp_[ci + j];
  #pragma unroll
  for(int j = 0; j < 4; j++)
    other[j] = __shfl_xor(mine[j], 32, 64);
  if(low){
    bf16x4 o1, o2;
    #pragma unroll
    for(int j = 0; j < 4; j++){
      float cs = mine[j], td = other[j];
      o1[j] = (bf16)(fmaxf(cs, 0.f) + fmaxf(td, 0.f));
      o2[j] = (bf16)(cs + td);
    }
    *(bf16x4*)(V + (size_t)row * 256 + lane * 4)       = o1;
    *(bf16x4*)(V + (size_t)row * 256 + 128 + lane * 4) = o2;
  }
}

// ---------------- K5: final GEMM + fused LayerNorm ----------------
__global__ __launch_bounds__(128, 3) void k5_cat_ln(
    const bf16* __restrict__ V, const bf16* __restrict__ Wg, float* __restrict__ res,
    int M, int K,
    const float* __restrict__ bias, const float* __restrict__ lng, const float* __restrict__ lnb){
  __shared__ bf16 Bs[3][4096];
  gemm_body<1, 2, 1>(Bs, blockIdx.x, 0, nullptr, V, Wg, res, nullptr,
                     M, K, 8, 8, 0, 0, nullptr, bias, lng, lnb);
}

// ---------------- launch ----------------

extern "C" void kernel_launch(void* const* d_in, const int* in_sizes, int n_in,
                              void* d_out, int out_size, void* d_ws, size_t ws_size,
                              hipStream_t stream){
  const float* curr_h   = (const float*)d_in[0];
  const float* next_h   = (const float*)d_in[1];
  const float* curr_inc = (const float*)d_in[2];
  const int*   src      = (const int*)d_in[3];
  const int*   dst      = (const int*)d_in[4];
  const float* W_conv   = (const float*)d_in[5];
  const float* b_conv   = (const float*)d_in[6];
  const float* W_fus    = (const float*)d_in[7];
  const float* b_fus    = (const float*)d_in[8];
  const float* conv_w   = (const float*)d_in[9];
  const float* td_w     = (const float*)d_in[10];
  const float* cat_W    = (const float*)d_in[11];
  const float* cat_b    = (const float*)d_in[12];
  const float* ln_g     = (const float*)d_in[13];
  const float* ln_b     = (const float*)d_in[14];

  const int D    = LG_D;
  const int M    = in_sizes[0] / D;      // 20000
  const int Kinc = in_sizes[1] / D;      // 10000
  const int E    = in_sizes[3];          // 320000
  const int K2   = in_sizes[11] / D;     // 256

  const int TOT1    = (Kinc + 31) / 32;  // 313 BK=32 tiles
  const int K8ALLOC = (TOT1 + 3) * 4;    // 1264 k8-groups (incl. depth-3 overrun pad)
  const int NBIG    = (K8ALLOC * 128) / 256;  // 632 granulate blocks for Bg

  // workspace carve (256B aligned)
  char* p = (char*)d_ws;
  auto alloc = [&](size_t bytes){ char* q = p; p += (bytes + 255) & ~(size_t)255; return q; };
  bf16*  H      = (bf16*) alloc((size_t)M * 256 * 2);
  bf16*  V      = (bf16*) alloc((size_t)M * 256 * 2);
  bf16*  Bg     = (bf16*) alloc((size_t)K8ALLOC * 128 * 16);
  bf16*  Wcg    = (bf16*) alloc((size_t)32 * 128 * 16);    // k8 pad to 32
  bf16*  Wfg    = (bf16*) alloc((size_t)32 * 128 * 16);
  bf16*  catWg  = (bf16*) alloc((size_t)48 * 128 * 16);    // k8 pad to 48
  int*   cnts   = (int*)  alloc((size_t)2 * M * 4);        // cnt_in | cnt_out
  int*   q      = (int*)  alloc((size_t)M * 4);            // CSR starts -> ends
  int*   csr    = (int*)  alloc((size_t)E * 4);
  int* cnt_in  = cnts;
  int* cnt_out = cnts + M;
  (void)ws_size; (void)n_in; (void)out_size;

  float* res = (float*)d_out;
  const int gm = (M + 31) / 32;          // 625

  // 1. zero degree counters
  zero_kernel<<<(2 * M + 255) / 256, 256, 0, stream>>>(cnts, 2 * M);

  // 2. granulate all B matrices + edge histogram (merged, independent work)
  k1_gran_hist<<<NBIG + 56 + (E + 255) / 256, 256, 0, stream>>>(
      next_h, W_conv, W_fus, cat_W, Bg, Wcg, Wfg, catWg, Kinc, NBIG,
      src, dst, cnt_out, cnt_in, E);

  // 3. mega dispatch: 800MB inc stream (full-K, depth-3) with barrier-free
  //    W_fus fusion -> H[:,128:256]; curr_h GEMM -> H[:,0:128]; scan -> q.
  //    1251 blocks, 5/CU LDS cap -> all co-resident.
  k2_mega<<<2 * gm + 1, 128, 0, stream>>>(
      curr_inc, Bg, Wfg, Wcg, curr_h, H, M, Kinc, TOT1, cnt_out, cnt_in, q, gm);

  // 4. CSR scatter (q: starts -> ends)
  k3_scatter<<<(E + 255) / 256, 256, 0, stream>>>(src, dst, q, csr, E);

  // 5. SpMM + normalize + bias + channel weights + relu/concat -> V[M][256] bf16
  spmm_fuse_kernel<<<(M + 3) / 4, 256, 0, stream>>>(H, q, csr,
                                          b_conv, conv_w, b_fus, td_w, V, M);

  // 6+7. res = LayerNorm(V @ cat_W + cat_b)  (LN fused into epilogue)
  k5_cat_ln<<<gm, 128, 0, stream>>>(V, catWg, res, M, K2, cat_b, ln_g, ln_b);
}